// Round 11
// baseline (286.599 us; speedup 1.0000x reference)
//
#include <hip/hip_runtime.h>
#include <hip/hip_bf16.h>

#define B_    32
#define C_    512
#define S_    1024
#define G_    32
#define CPG_  16
#define EPS_  1e-5f
#define SCALE_ 0.044194173824159216f   // 1/sqrt(512), folded into Wz during prep
#define ZS_    1024.0f                  // Wz fp8 scale (2^10); descale in exp arg
#define VS_    1048576.0f               // Wvo fp8 scale (2^20); descale in pv epilogue
#define INVZS_ 0.0009765625f
#define INVVS_ 9.5367431640625e-07f

typedef __attribute__((ext_vector_type(4))) float  floatx4;
typedef __attribute__((ext_vector_type(8))) __bf16 bf16x8;
typedef long lng;

__device__ __forceinline__ float bf2f(unsigned short u) {
    union { unsigned int i; float f; } v; v.i = ((unsigned int)u) << 16; return v.f;
}
__device__ __forceinline__ unsigned short f2bf(float f) {
    union { float f; unsigned int i; } v; v.f = f;
    unsigned int r = v.i + 0x7fffu + ((v.i >> 16) & 1u);
    return (unsigned short)(r >> 16);
}
// 4x f32 -> 4x OCP e4m3 bytes via native v_cvt_pk_fp8_f32 (saturating RNE on gfx950)
__device__ __forceinline__ unsigned int f2f8x4(float a, float b, float c, float d) {
    unsigned int v = (unsigned int)__builtin_amdgcn_cvt_pk_fp8_f32(a, b, 0, false);
    v = (unsigned int)__builtin_amdgcn_cvt_pk_fp8_f32(c, d, (int)v, true);
    return v;
}

// direct global->LDS DMA, 16 bytes per lane. LDS dest = wave-uniform base + lane*16.
__device__ __forceinline__ void gl16(const void* g, void* l) {
    __builtin_amdgcn_global_load_lds(
        (const __attribute__((address_space(1))) unsigned int*)g,
        (__attribute__((address_space(3))) unsigned int*)l, 16, 0, 0);
}

// ---------------- fused group-norm + transpose + fp8 cast (x read ONCE) ----------------
__global__ __launch_bounds__(256) void gnxnt(const float* __restrict__ x,
                                             const float* __restrict__ gamma,
                                             const float* __restrict__ beta,
                                             unsigned char* __restrict__ xnt,
                                             float* __restrict__ lbuf) {
    const int bid = blockIdx.x;
    const int b = bid >> 5, g = bid & 31;
    if (threadIdx.x < 8)
        ((float4*)lbuf)[bid * 8 + threadIdx.x] = make_float4(0.f, 0.f, 0.f, 0.f);

    __shared__ float tile[16 * 1025];
    __shared__ float a1[4], a2[4];
    const float* xb = x + (size_t)b * (C_ * S_) + (size_t)g * (CPG_ * S_);
    const int t = threadIdx.x;

    float s = 0.f, ss = 0.f;
    #pragma unroll
    for (int k = 0; k < 16; k++) {
        int idx = t + k * 256;
        float4 v = ((const float4*)xb)[idx];
        int c = idx >> 8, s4 = (idx & 255) * 4;
        float* dst = tile + c * 1025 + s4;
        dst[0] = v.x; dst[1] = v.y; dst[2] = v.z; dst[3] = v.w;
        s  += v.x + v.y + v.z + v.w;
        ss += v.x * v.x + v.y * v.y + v.z * v.z + v.w * v.w;
    }
    #pragma unroll
    for (int o = 32; o; o >>= 1) { s += __shfl_down(s, o); ss += __shfl_down(ss, o); }
    const int wid = t >> 6, lane = t & 63;
    if (lane == 0) { a1[wid] = s; a2[wid] = ss; }
    __syncthreads();
    float S  = a1[0] + a1[1] + a1[2] + a1[3];
    float SS = a2[0] + a2[1] + a2[2] + a2[3];
    float mean = S * (1.f / 16384.f);
    float var  = SS * (1.f / 16384.f) - mean * mean;
    float rstd = rsqrtf(var + EPS_);

    const int c0 = g * 16, cc = (t & 3) * 4;
    float av[4], bv[4];
    #pragma unroll
    for (int i = 0; i < 4; i++) {
        float a_ = rstd * gamma[c0 + cc + i];
        av[i] = a_; bv[i] = beta[c0 + cc + i] - mean * a_;
    }
    unsigned char* xo = xnt + (size_t)b * (S_ * C_) + c0 + cc;
    #pragma unroll
    for (int p = 0; p < 16; p++) {
        int srow = p * 64 + (t >> 2);
        const float* col = tile + srow;
        unsigned int o4 = f2f8x4(av[0] * col[(cc + 0) * 1025] + bv[0],
                                 av[1] * col[(cc + 1) * 1025] + bv[1],
                                 av[2] * col[(cc + 2) * 1025] + bv[2],
                                 av[3] * col[(cc + 3) * 1025] + bv[3]);
        *(unsigned int*)(xo + (size_t)srow * C_) = o4;
    }
}

// ---------------- weight prep: transpose+cast WqT/WkT/WvT (z<3), plain cast Woutb (z==3) ----
__global__ __launch_bounds__(256) void tcast(const float* __restrict__ w,
                                             const float* __restrict__ w_out,
                                             unsigned short* __restrict__ WqT,
                                             unsigned short* __restrict__ WkT,
                                             unsigned short* __restrict__ WvT,
                                             unsigned short* __restrict__ Woutb) {
    const int z = blockIdx.z;
    const int m0 = blockIdx.y * 64, c0 = blockIdx.x * 64;
    const int t = threadIdx.x, tr = t >> 4, tc4 = (t & 15) * 4;
    if (z == 3) {
        #pragma unroll
        for (int i = 0; i < 4; i++) {
            int r = tr + i * 16;
            float4 v = *(const float4*)(w_out + (size_t)(m0 + r) * 512 + c0 + tc4);
            ushort4 o4;
            o4.x = f2bf(v.x); o4.y = f2bf(v.y); o4.z = f2bf(v.z); o4.w = f2bf(v.w);
            *(ushort4*)(Woutb + (size_t)(m0 + r) * 512 + c0 + tc4) = o4;
        }
        return;
    }
    const float* src = w + (size_t)z * 262144;
    unsigned short* dst = (z == 0) ? WqT : (z == 1) ? WkT : WvT;
    __shared__ float tile[64][65];
    #pragma unroll
    for (int i = 0; i < 4; i++) {
        int r = tr + i * 16;
        float4 v = *(const float4*)(src + (size_t)(m0 + r) * 512 + c0 + tc4);
        tile[r][tc4 + 0] = v.x; tile[r][tc4 + 1] = v.y;
        tile[r][tc4 + 2] = v.z; tile[r][tc4 + 3] = v.w;
    }
    __syncthreads();
    #pragma unroll
    for (int i = 0; i < 4; i++) {
        int sr = tr + i * 16;
        ushort4 o4;
        o4.x = f2bf(tile[tc4 + 0][sr]); o4.y = f2bf(tile[tc4 + 1][sr]);
        o4.z = f2bf(tile[tc4 + 2][sr]); o4.w = f2bf(tile[tc4 + 3][sr]);
        *(ushort4*)(dst + (size_t)(c0 + sr) * 512 + m0 + tc4) = o4;
    }
}

// ---------------- bias prep: us = ZS*SCALE*(bq.Wk), bvo = VS*(Wout.bv) ----------------
__global__ __launch_bounds__(256) void vecprep(const unsigned short* __restrict__ WkT,
                                               const float* __restrict__ w_out,
                                               const float* __restrict__ b_qkv,
                                               float* __restrict__ bzv) {
    const int o = blockIdx.x, t = threadIdx.x;
    float us = 0.f, bv = 0.f;
    #pragma unroll
    for (int mm = 0; mm < 2; mm++) {
        int m = t + mm * 256;
        us += b_qkv[m] * bf2f(WkT[(size_t)o * 512 + m]);
        bv += w_out[(size_t)o * 512 + m] * b_qkv[1024 + m];
    }
    #pragma unroll
    for (int sh = 32; sh; sh >>= 1) { us += __shfl_down(us, sh); bv += __shfl_down(bv, sh); }
    __shared__ float a[2][4];
    const int wid = t >> 6, lane = t & 63;
    if (lane == 0) { a[0][wid] = us; a[1][wid] = bv; }
    __syncthreads();
    if (t == 0) {
        bzv[o]       = (a[0][0] + a[0][1] + a[0][2] + a[0][3]) * SCALE_ * ZS_;
        bzv[512 + o] = (a[1][0] + a[1][1] + a[1][2] + a[1][3]) * VS_;
    }
}

// ---------------- 128x128 bf16 MFMA loop (BK=64) — for tiny prep GEMMs ----------------
template<bool SWAP>
__device__ __forceinline__ void mfma_loop(const unsigned short* __restrict__ Ag, int lda,
                                          const unsigned short* __restrict__ Bg, int ldb,
                                          int K, int m0, int n0,
                                          unsigned short* ldsA, unsigned short* ldsB,
                                          floatx4 (&acc)[4][4]) {
    const int t = threadIdx.x, lane = t & 63, wave = t >> 6;
    const int wr = (wave >> 1) * 64, wc = (wave & 1) * 64;
    const int lrow = lane & 15, lq = lane >> 4;
    const int srow = wave * 16 + (lane >> 2);
    const int scol = (lane & 3) * 8;
    const unsigned short* gA0 = Ag + (size_t)(m0 + srow) * lda + scol;
    const unsigned short* gA1 = gA0 + (size_t)64 * lda;
    const unsigned short* gB0 = Bg + (size_t)(n0 + srow) * ldb + scol;
    const unsigned short* gB1 = gB0 + (size_t)64 * ldb;
    unsigned short* lA = ldsA + wave * 512;
    unsigned short* lB = ldsB + wave * 512;
    for (int k0 = 0; k0 < K; k0 += 64) {
        gl16(gA0 + k0,      lA);
        gl16(gA1 + k0,      lA + 2048);
        gl16(gA0 + k0 + 32, lA + 4096);
        gl16(gA1 + k0 + 32, lA + 6144);
        gl16(gB0 + k0,      lB);
        gl16(gB1 + k0,      lB + 2048);
        gl16(gB0 + k0 + 32, lB + 4096);
        gl16(gB1 + k0 + 32, lB + 6144);
        __syncthreads();
        #pragma unroll
        for (int sub = 0; sub < 2; sub++) {
            bf16x8 af[4], bfr[4];
            #pragma unroll
            for (int i = 0; i < 4; i++) {
                af[i]  = *(const bf16x8*)(ldsA + sub * 4096 + (wr + i * 16 + lrow) * 32 + lq * 8);
                bfr[i] = *(const bf16x8*)(ldsB + sub * 4096 + (wc + i * 16 + lrow) * 32 + lq * 8);
            }
            #pragma unroll
            for (int i = 0; i < 4; i++)
                #pragma unroll
                for (int j = 0; j < 4; j++) {
                    if (SWAP)
                        acc[i][j] = __builtin_amdgcn_mfma_f32_16x16x32_bf16(bfr[j], af[i], acc[i][j], 0, 0, 0);
                    else
                        acc[i][j] = __builtin_amdgcn_mfma_f32_16x16x32_bf16(af[i], bfr[j], acc[i][j], 0, 0, 0);
                }
        }
        __syncthreads();
    }
}

// Wz' = ZS*SCALE*(Wk^T.Wq) (rows 0-511, fp8);  Wvo' = VS*(Wout.Wv) (rows 512-1023, fp8).
__global__ __launch_bounds__(256) void prep_gemm(const unsigned short* __restrict__ WkT,
                                                 const unsigned short* __restrict__ WqT,
                                                 const unsigned short* __restrict__ Woutb,
                                                 const unsigned short* __restrict__ WvT,
                                                 unsigned char* __restrict__ Wzv) {
    __shared__ __align__(16) unsigned short ldsA[2 * 128 * 32];
    __shared__ __align__(16) unsigned short ldsB[2 * 128 * 32];
    const int z = blockIdx.z;
    const int m0 = blockIdx.y * 128, n0 = blockIdx.x * 128;
    const int t = threadIdx.x, lane = t & 63, wave = t >> 6;
    const int wr = (wave >> 1) * 64, wc = (wave & 1) * 64;
    const int lrow = lane & 15, lq = lane >> 4;
    floatx4 acc[4][4];
    #pragma unroll
    for (int i = 0; i < 4; i++)
        #pragma unroll
        for (int j = 0; j < 4; j++) acc[i][j] = (floatx4){0.f, 0.f, 0.f, 0.f};
    const unsigned short* Ag = z ? Woutb : WkT;
    const unsigned short* Bg = z ? WvT   : WqT;
    mfma_loop<true>(Ag, 512, Bg, 512, 512, m0, n0, ldsA, ldsB, acc);
    const float sc = z ? VS_ : (SCALE_ * ZS_);
    #pragma unroll
    for (int i = 0; i < 4; i++)
        #pragma unroll
        for (int j = 0; j < 4; j++) {
            int row = z * 512 + m0 + wr + i * 16 + lrow;
            int col = n0 + wc + j * 16 + lq * 4;
            floatx4 v = acc[i][j];
            unsigned int o4 = f2f8x4(v[0] * sc, v[1] * sc, v[2] * sc, v[3] * sc);
            *(unsigned int*)(Wzv + (size_t)row * 512 + col) = o4;
        }
}

// ================= 256x256 2-phase-per-tile FP8 MFMA mainloop (BK=128) =================
// Same LDS geometry/swizzle as the R10-verified loop: per operand [buf2][kh2][256 rows][64 B],
// 16B-slot XOR swizzle. Phases merged: one phase per kh slab = 24 ds_read_b64 + 4 gl16
// stage + 64 MFMA between one barrier pair (was 4 phases x 32 MFMA). Barriers/tile 8->4.
// Ledger: prologue stages T0 (8 loads), vmcnt(4). Each phase stages u+1's same-kh slabs
// (4 loads) and ends vmcnt(4)+barrier; last tile: vmcnt(0) after kh0, fall-through after
// kh1. Per-acc accumulate order (kh0ks0, kh0ks1, kh1ks0, kh1ks1) identical to R10.
template<bool SWAP>
__device__ __forceinline__ void mfma256f8_loop(const unsigned char* __restrict__ Ag, int lda,
                                               const unsigned char* __restrict__ Bg, int ldb,
                                               int nt, int m0, int n0,
                                               unsigned char* lds, floatx4 (&acc)[8][4]) {
    const int tid  = threadIdx.x;
    const int lane = tid & 63, wave = tid >> 6;
    const int wm = wave >> 2, wn = wave & 3;
    const int lrow = lane & 15, lq = lane >> 4;
    const int swz  = (lrow >> 1) & 3;
    const int hb   = (lq & 1) * 8;
    const int slb  = lq >> 1;
    const int s0 = ((slb    ) ^ swz) * 16 + hb;   // ks=0 fragment offset within row
    const int s1 = ((slb + 2) ^ swz) * 16 + hb;   // ks=1

    int aof[8], bof[4];
    #pragma unroll
    for (int i = 0; i < 8; i++) aof[i] = (wm * 128 + i * 16 + lrow) * 64;
    #pragma unroll
    for (int j = 0; j < 4; j++) bof[j] = 65536 + (wn * 64 + j * 16 + lrow) * 64;

    const int sr  = tid >> 2;
    const int scs = (tid & 3) ^ ((tid >> 3) & 3);
    const unsigned char* gA = Ag + (size_t)(m0 + sr) * lda + scs * 16;
    const unsigned char* gB = Bg + (size_t)(n0 + sr) * ldb + scs * 16;
    const size_t a128 = (size_t)128 * lda, b128 = (size_t)128 * ldb;
    unsigned char* lwA = lds + wave * 1024;
    unsigned char* lwB = lds + 65536 + wave * 1024;

#define STAGE_A(t, kh) do { \
    unsigned char* lb_ = lwA + ((t) & 1) * 32768 + (kh) * 16384; \
    const unsigned char* gp_ = gA + (t) * 128 + (kh) * 64; \
    gl16(gp_, lb_); gl16(gp_ + a128, lb_ + 8192); } while (0)
#define STAGE_B(t, kh) do { \
    unsigned char* lb_ = lwB + ((t) & 1) * 32768 + (kh) * 16384; \
    const unsigned char* gp_ = gB + (t) * 128 + (kh) * 64; \
    gl16(gp_, lb_); gl16(gp_ + b128, lb_ + 8192); } while (0)

    // prologue: stage T0 fully (8 loads); wait for its kh0 half (leave kh1's 4 in flight)
    STAGE_A(0, 0); STAGE_B(0, 0); STAGE_A(0, 1); STAGE_B(0, 1);
    asm volatile("s_waitcnt vmcnt(4)" ::: "memory");
    __builtin_amdgcn_s_barrier();

    lng af0[8], af1[8], bf0[4], bf1[4];
    for (int u = 0; u < nt; ++u) {
        const int p = u & 1;
        #pragma unroll
        for (int kh = 0; kh < 2; ++kh) {
            const int slab = p * 32768 + kh * 16384;
            #pragma unroll
            for (int j = 0; j < 4; j++) {
                bf0[j] = *(const lng*)(lds + slab + bof[j] + s0);
                bf1[j] = *(const lng*)(lds + slab + bof[j] + s1);
            }
            #pragma unroll
            for (int i = 0; i < 8; i++) {
                af0[i] = *(const lng*)(lds + slab + aof[i] + s0);
                af1[i] = *(const lng*)(lds + slab + aof[i] + s1);
            }
            if (u + 1 < nt) { STAGE_A(u + 1, kh); STAGE_B(u + 1, kh); }
            __builtin_amdgcn_s_barrier();
            asm volatile("s_waitcnt lgkmcnt(0)" ::: "memory");
            __builtin_amdgcn_sched_barrier(0);
            __builtin_amdgcn_s_setprio(1);
            #pragma unroll
            for (int i = 0; i < 8; i++)
                #pragma unroll
                for (int j = 0; j < 4; j++) {
                    if (SWAP)
                        acc[i][j] = __builtin_amdgcn_mfma_f32_16x16x32_fp8_fp8(
                            bf0[j], af0[i], acc[i][j], 0, 0, 0);
                    else
                        acc[i][j] = __builtin_amdgcn_mfma_f32_16x16x32_fp8_fp8(
                            af0[i], bf0[j], acc[i][j], 0, 0, 0);
                }
            #pragma unroll
            for (int i = 0; i < 8; i++)
                #pragma unroll
                for (int j = 0; j < 4; j++) {
                    if (SWAP)
                        acc[i][j] = __builtin_amdgcn_mfma_f32_16x16x32_fp8_fp8(
                            bf1[j], af1[i], acc[i][j], 0, 0, 0);
                    else
                        acc[i][j] = __builtin_amdgcn_mfma_f32_16x16x32_fp8_fp8(
                            af1[i], bf1[j], acc[i][j], 0, 0, 0);
                }
            __builtin_amdgcn_s_setprio(0);
            if (u < nt - 1) {
                asm volatile("s_waitcnt vmcnt(4)" ::: "memory");   // next slab landed
                __builtin_amdgcn_s_barrier();
            } else if (kh == 0) {
                asm volatile("s_waitcnt vmcnt(0)" ::: "memory");   // final drain
                __builtin_amdgcn_s_barrier();
            }   // (nt-1, kh1): fall through to epilogue
        }
    }
#undef STAGE_A
#undef STAGE_B
}

// common body vars (b, m0, n0 must be defined by the kernel before this)
#define GEMMF8_VARS                                                   \
    __shared__ __align__(16) unsigned char lds[131072];               \
    const int lane = threadIdx.x & 63, wave = threadIdx.x >> 6;       \
    const int wm = wave >> 2, wn = wave & 3;                          \
    const int lrow = lane & 15, lq = lane >> 4;                       \
    floatx4 acc[8][4];                                                \
    _Pragma("unroll") for (int i = 0; i < 8; i++)                     \
        _Pragma("unroll") for (int j = 0; j < 4; j++)                 \
            acc[i][j] = (floatx4){0.f, 0.f, 0.f, 0.f};

// ---------------- ZV projection: Z' = Xn.Wz'^T + us' (rows 0-511), V'' = Xn.Wvo'^T + bvo' ----
__global__ __launch_bounds__(512, 2) void zv_mfma(const unsigned char* __restrict__ Wzv,
                                                  const unsigned char* __restrict__ xnt,
                                                  const float* __restrict__ bzv,
                                                  unsigned char* __restrict__ Zb,
                                                  unsigned char* __restrict__ Vb) {
    const int f = blockIdx.x;                 // 512 blocks
    const int xcd = f & 7, j = f >> 3;
    const int b = xcd + 8 * (j >> 4);
    const int tile = j & 15;
    const int m0 = (tile >> 2) * 256, n0 = (tile & 3) * 256;
    GEMMF8_VARS
    const unsigned char* Bg = xnt + (size_t)b * (S_ * C_);
    if (m0 < 512) {
        mfma256f8_loop<false>(Wzv, C_, Bg, C_, 4, m0, n0, lds, acc);
        unsigned char* dst = Zb + (size_t)b * (S_ * C_);
        #pragma unroll
        for (int i = 0; i < 8; i++)
            #pragma unroll
            for (int j2 = 0; j2 < 4; j2++) {
                int oabs = m0 + wm * 128 + i * 16 + lq * 4;
                int s    = n0 + wn * 64 + j2 * 16 + lrow;
                float4 bi = *(const float4*)(bzv + oabs);
                floatx4 v = acc[i][j2];
                unsigned int o4 = f2f8x4(v[0] + bi.x, v[1] + bi.y,
                                         v[2] + bi.z, v[3] + bi.w);
                *(unsigned int*)(dst + (size_t)s * C_ + oabs) = o4;
            }
    } else {
        mfma256f8_loop<true>(Wzv, C_, Bg, C_, 4, m0, n0, lds, acc);
        unsigned char* dst = Vb + (size_t)b * (C_ * S_);
        #pragma unroll
        for (int i = 0; i < 8; i++)
            #pragma unroll
            for (int j2 = 0; j2 < 4; j2++) {
                int row = m0 + wm * 128 + i * 16 + lrow;
                int c   = row - 512;
                int sb  = n0 + wn * 64 + j2 * 16 + lq * 4;
                float bi = bzv[row];
                floatx4 v = acc[i][j2];
                unsigned int o4 = f2f8x4(v[0] + bi, v[1] + bi, v[2] + bi, v[3] + bi);
                *(unsigned int*)(dst + (size_t)c * S_ + sb) = o4;
            }
    }
}

// ---------------- scores+exp: P[s][kv] = exp((Z'.Xn)/ZS) fp8, row-sums -> l (f32) ----------
__global__ __launch_bounds__(512, 2) void scores_exp(const unsigned char* __restrict__ Zb,
                                                     const unsigned char* __restrict__ xnt,
                                                     unsigned char* __restrict__ Pb,
                                                     float* __restrict__ l) {
    const int f = blockIdx.x;                 // 512 blocks
    const int xcd = f & 7, j = f >> 3;
    const int b = xcd + 8 * (j >> 4);
    const int tile = j & 15;
    const int m0 = (tile >> 2) * 256, n0 = (tile & 3) * 256;
    GEMMF8_VARS
    const unsigned char* Ag = Zb  + (size_t)b * (S_ * C_);
    const unsigned char* Bg = xnt + (size_t)b * (S_ * C_);
    mfma256f8_loop<true>(Ag, C_, Bg, C_, 4, m0, n0, lds, acc);
    unsigned char* pp = Pb + (size_t)b * ((size_t)S_ * S_);
    float* lb = l + b * S_;
    float rsv[8];
    #pragma unroll
    for (int i = 0; i < 8; i++) {
        int q = m0 + wm * 128 + i * 16 + lrow;
        float rs = 0.f;
        #pragma unroll
        for (int j2 = 0; j2 < 4; j2++) {
            int kv = n0 + wn * 64 + j2 * 16 + lq * 4;
            floatx4 v = acc[i][j2];
            float e0 = __expf(v[0] * INVZS_), e1 = __expf(v[1] * INVZS_);
            float e2 = __expf(v[2] * INVZS_), e3 = __expf(v[3] * INVZS_);
            rs += (e0 + e1) + (e2 + e3);
            *(unsigned int*)(pp + (size_t)q * S_ + kv) = f2f8x4(e0, e1, e2, e3);
        }
        rs += __shfl_xor(rs, 16);
        rs += __shfl_xor(rs, 32);
        rsv[i] = rs;                                  // valid in lanes < 16
    }
    __syncthreads();
    float* sred = (float*)lds;                        // [4 wn][256 qloc]
    if (lane < 16) {
        #pragma unroll
        for (int i = 0; i < 8; i++)
            sred[wn * 256 + wm * 128 + i * 16 + lrow] = rsv[i];
    }
    __syncthreads();
    if (threadIdx.x < 256) {
        int q = threadIdx.x;
        float sum = (sred[q] + sred[256 + q]) + (sred[512 + q] + sred[768 + q]);
        atomicAdd(lb + m0 + q, sum);
    }
}

// ---------------- PV + normalize (incl. 1/VS) + bias + residual -> f32 out ----------------
__global__ __launch_bounds__(512, 2) void pv_out(const unsigned char* __restrict__ Vb,
                                                 const unsigned char* __restrict__ Pb,
                                                 const float* __restrict__ l,
                                                 const float* __restrict__ bout,
                                                 const float* __restrict__ x,
                                                 float* __restrict__ out) {
    const int f = blockIdx.x;                 // 256 blocks
    const int xcd = f & 7, j = f >> 3;
    const int b = xcd + 8 * (j >> 3);
    const int tile = j & 7;
    const int m0 = (tile & 1) * 256, n0 = (tile >> 1) * 256;
    GEMMF8_VARS
    const unsigned char* Ag = Vb + (size_t)b * (C_ * S_);
    const unsigned char* Bg = Pb + (size_t)b * ((size_t)S_ * S_);
    mfma256f8_loop<true>(Ag, S_, Bg, S_, 8, m0, n0, lds, acc);
    const float* lb = l + b * S_;
    const float* xb = x + (size_t)b * (C_ * S_);
    float* ob = out + (size_t)b * (C_ * S_);
    #pragma unroll
    for (int i = 0; i < 8; i++) {
        int c = m0 + wm * 128 + i * 16 + lrow;
        float bb = bout[c];
        #pragma unroll
        for (int j2 = 0; j2 < 4; j2++) {
            int s = n0 + wn * 64 + j2 * 16 + lq * 4;
            float4 lv = *(const float4*)(lb + s);
            size_t idx = (size_t)c * S_ + s;
            float4 xv = *(const float4*)(xb + idx);
            floatx4 v = acc[i][j2];
            float4 r;
            r.x = v[0] * (__frcp_rn(lv.x) * INVVS_) + bb + xv.x;
            r.y = v[1] * (__frcp_rn(lv.y) * INVVS_) + bb + xv.y;
            r.z = v[2] * (__frcp_rn(lv.z) * INVVS_) + bb + xv.z;
            r.w = v[3] * (__frcp_rn(lv.w) * INVVS_) + bb + xv.w;
            *(float4*)(ob + idx) = r;
        }
    }
}

// ---------------- launch ----------------
extern "C" void kernel_launch(void* const* d_in, const int* in_sizes, int n_in,
                              void* d_out, int out_size, void* d_ws, size_t ws_size,
                              hipStream_t stream) {
    const float* x      = (const float*)d_in[0];
    const float* gamma  = (const float*)d_in[1];
    const float* beta   = (const float*)d_in[2];
    const float* w_qkv  = (const float*)d_in[3];
    const float* b_qkv  = (const float*)d_in[4];
    const float* w_out  = (const float*)d_in[5];
    const float* b_out  = (const float*)d_in[6];
    float* out          = (float*)d_out;

    char* ws = (char*)d_ws;
    // layout (bytes), all attention tensors fp8 (1 B):
    //   Zb   [b][1024][512] @ 0       (16 MB)
    //   Vb   [b][512][1024] @ 16 MB   (16 MB)   (V'' = VS*(Xn.Wvo^T)+bvo')
    //   xnt  [b][1024][512] @ 32 MB   (16 MB)
    //   Pb   [b][1024][1024] @ 48 MB  (32 MB)   (unnormalized exp)
    //   @96 MB: WqT/WkT/WvT/Woutb bf16 (4 x 512 KB), Wzv fp8 (512 KB), bzv, lbuf
    unsigned char* Zb    = (unsigned char*)(ws);
    unsigned char* Vb    = (unsigned char*)(ws + 16777216ULL);
    unsigned char* xnt   = (unsigned char*)(ws + 33554432ULL);
    unsigned char* Pb    = (unsigned char*)(ws + 50331648ULL);
    unsigned short* WqT   = (unsigned short*)(ws + 100663296ULL);
    unsigned short* WkT   = (unsigned short*)(ws + 100663296ULL + 524288ULL);
    unsigned short* WvT   = (unsigned short*)(ws + 100663296ULL + 1048576ULL);
    unsigned short* Woutb = (unsigned short*)(ws + 100663296ULL + 1572864ULL);
    unsigned char*  Wzv   = (unsigned char*)(ws + 100663296ULL + 2097152ULL);
    float*          bzv   = (float*)(ws + 100663296ULL + 2621440ULL);
    float*          lbuf  = (float*)(ws + 100663296ULL + 2629632ULL);

    gnxnt    <<<B_ * G_, 256, 0, stream>>>(x, gamma, beta, xnt, lbuf);
    tcast    <<<dim3(8, 8, 4), 256, 0, stream>>>(w_qkv, w_out, WqT, WkT, WvT, Woutb);
    prep_gemm<<<dim3(4, 4, 2), 256, 0, stream>>>(WkT, WqT, Woutb, WvT, Wzv);
    vecprep  <<<512, 256, 0, stream>>>(WkT, w_out, b_qkv, bzv);
    zv_mfma  <<<512, 512, 0, stream>>>(Wzv, xnt, bzv, Zb, Vb);
    scores_exp<<<512, 512, 0, stream>>>(Zb, xnt, Pb, lbuf);
    pv_out   <<<256, 512, 0, stream>>>(Vb, Pb, lbuf, b_out, x, out);
}

// Round 12
// 274.035 us; speedup vs baseline: 1.0458x; 1.0458x over previous
//
#include <hip/hip_runtime.h>
#include <hip/hip_bf16.h>

#define B_    32
#define C_    512
#define S_    1024
#define G_    32
#define CPG_  16
#define EPS_  1e-5f
#define SCALE_ 0.044194173824159216f   // 1/sqrt(512), folded into Wz during prep
#define ZS_    1024.0f                  // Wz fp8 scale (2^10); descale in exp arg
#define VS_    1048576.0f               // Wvo fp8 scale (2^20); descale in pv epilogue
#define INVZS_ 0.0009765625f
#define INVVS_ 9.5367431640625e-07f

typedef __attribute__((ext_vector_type(4))) float  floatx4;
typedef __attribute__((ext_vector_type(8))) __bf16 bf16x8;
typedef long lng;

__device__ __forceinline__ float bf2f(unsigned short u) {
    union { unsigned int i; float f; } v; v.i = ((unsigned int)u) << 16; return v.f;
}
__device__ __forceinline__ unsigned short f2bf(float f) {
    union { float f; unsigned int i; } v; v.f = f;
    unsigned int r = v.i + 0x7fffu + ((v.i >> 16) & 1u);
    return (unsigned short)(r >> 16);
}
// 4x f32 -> 4x OCP e4m3 bytes via native v_cvt_pk_fp8_f32 (saturating RNE on gfx950)
__device__ __forceinline__ unsigned int f2f8x4(float a, float b, float c, float d) {
    unsigned int v = (unsigned int)__builtin_amdgcn_cvt_pk_fp8_f32(a, b, 0, false);
    v = (unsigned int)__builtin_amdgcn_cvt_pk_fp8_f32(c, d, (int)v, true);
    return v;
}

// direct global->LDS DMA, 16 bytes per lane. LDS dest = wave-uniform base + lane*16.
__device__ __forceinline__ void gl16(const void* g, void* l) {
    __builtin_amdgcn_global_load_lds(
        (const __attribute__((address_space(1))) unsigned int*)g,
        (__attribute__((address_space(3))) unsigned int*)l, 16, 0, 0);
}

// ============ fused prep: gnxnt (blocks 0-1023) || tcast (1024-1279) || vecprep (1280-1791) ====
// All three are mutually independent; merging hides the weight-prep under gnxnt's memory time.
__global__ __launch_bounds__(256) void fused_prep(const float* __restrict__ x,
                                                  const float* __restrict__ gamma,
                                                  const float* __restrict__ beta,
                                                  const float* __restrict__ w_qkv,
                                                  const float* __restrict__ w_out,
                                                  unsigned char* __restrict__ xnt,
                                                  unsigned short* __restrict__ WqT,
                                                  unsigned short* __restrict__ WkT,
                                                  unsigned short* __restrict__ WvT,
                                                  unsigned short* __restrict__ Woutb,
                                                  float* __restrict__ bzv,
                                                  float* __restrict__ lbuf) {
    __shared__ float sh[16 * 1025 + 8];
    const int bid = blockIdx.x, t = threadIdx.x;

    if (bid < 1024) {
        // ---- gnxnt: group-norm + transpose + fp8 cast (x read ONCE); zero lbuf ----
        const int b = bid >> 5, g = bid & 31;
        if (t < 8)
            ((float4*)lbuf)[bid * 8 + t] = make_float4(0.f, 0.f, 0.f, 0.f);
        float* tile = sh;
        float* a1 = sh + 16 * 1025;
        float* a2 = a1 + 4;
        const float* xb = x + (size_t)b * (C_ * S_) + (size_t)g * (CPG_ * S_);
        float s = 0.f, ss = 0.f;
        #pragma unroll
        for (int k = 0; k < 16; k++) {
            int idx = t + k * 256;
            float4 v = ((const float4*)xb)[idx];
            int c = idx >> 8, s4 = (idx & 255) * 4;
            float* dst = tile + c * 1025 + s4;
            dst[0] = v.x; dst[1] = v.y; dst[2] = v.z; dst[3] = v.w;
            s  += v.x + v.y + v.z + v.w;
            ss += v.x * v.x + v.y * v.y + v.z * v.z + v.w * v.w;
        }
        #pragma unroll
        for (int o = 32; o; o >>= 1) { s += __shfl_down(s, o); ss += __shfl_down(ss, o); }
        const int wid = t >> 6, lane = t & 63;
        if (lane == 0) { a1[wid] = s; a2[wid] = ss; }
        __syncthreads();
        float S  = a1[0] + a1[1] + a1[2] + a1[3];
        float SS = a2[0] + a2[1] + a2[2] + a2[3];
        float mean = S * (1.f / 16384.f);
        float var  = SS * (1.f / 16384.f) - mean * mean;
        float rstd = rsqrtf(var + EPS_);
        const int c0 = g * 16, cc = (t & 3) * 4;
        float av[4], bv[4];
        #pragma unroll
        for (int i = 0; i < 4; i++) {
            float a_ = rstd * gamma[c0 + cc + i];
            av[i] = a_; bv[i] = beta[c0 + cc + i] - mean * a_;
        }
        unsigned char* xo = xnt + (size_t)b * (S_ * C_) + c0 + cc;
        #pragma unroll
        for (int p = 0; p < 16; p++) {
            int srow = p * 64 + (t >> 2);
            const float* col = tile + srow;
            unsigned int o4 = f2f8x4(av[0] * col[(cc + 0) * 1025] + bv[0],
                                     av[1] * col[(cc + 1) * 1025] + bv[1],
                                     av[2] * col[(cc + 2) * 1025] + bv[2],
                                     av[3] * col[(cc + 3) * 1025] + bv[3]);
            *(unsigned int*)(xo + (size_t)srow * C_) = o4;
        }
    } else if (bid < 1280) {
        // ---- tcast: transpose+cast WqT/WkT/WvT (z<3), plain cast Woutb (z==3) ----
        const int r4 = bid - 1024;
        const int z = r4 >> 6, rem = r4 & 63;
        const int m0 = (rem >> 3) * 64, c0 = (rem & 7) * 64;
        const int tr = t >> 4, tc4 = (t & 15) * 4;
        if (z == 3) {
            #pragma unroll
            for (int i = 0; i < 4; i++) {
                int r = tr + i * 16;
                float4 v = *(const float4*)(w_out + (size_t)(m0 + r) * 512 + c0 + tc4);
                ushort4 o4;
                o4.x = f2bf(v.x); o4.y = f2bf(v.y); o4.z = f2bf(v.z); o4.w = f2bf(v.w);
                *(ushort4*)(Woutb + (size_t)(m0 + r) * 512 + c0 + tc4) = o4;
            }
            return;
        }
        const float* src = w_qkv + (size_t)z * 262144;
        unsigned short* dst = (z == 0) ? WqT : (z == 1) ? WkT : WvT;
        float (*tile)[65] = (float(*)[65])sh;
        #pragma unroll
        for (int i = 0; i < 4; i++) {
            int r = tr + i * 16;
            float4 v = *(const float4*)(src + (size_t)(m0 + r) * 512 + c0 + tc4);
            tile[r][tc4 + 0] = v.x; tile[r][tc4 + 1] = v.y;
            tile[r][tc4 + 2] = v.z; tile[r][tc4 + 3] = v.w;
        }
        __syncthreads();
        #pragma unroll
        for (int i = 0; i < 4; i++) {
            int sr = tr + i * 16;
            ushort4 o4;
            o4.x = f2bf(tile[tc4 + 0][sr]); o4.y = f2bf(tile[tc4 + 1][sr]);
            o4.z = f2bf(tile[tc4 + 2][sr]); o4.w = f2bf(tile[tc4 + 3][sr]);
            *(ushort4*)(dst + (size_t)(c0 + sr) * 512 + m0 + tc4) = o4;
        }
    } else {
        // ---- vecprep (direct f32): us[o] = ZS*SCALE*sum_m bq[m]*w_qkv[(512+m)][o],
        //                            bvo[o] = VS*sum_m w_out[o][m]*bq[1024+m]
        const int o = bid - 1280;
        const float* bq = w_qkv;   // unused alias silencer
        (void)bq;
        float us = 0.f, bv = 0.f;
        #pragma unroll
        for (int mm = 0; mm < 2; mm++) {
            int m = t + mm * 256;
            us += gamma == nullptr ? 0.f : 0.f;   // no-op keep structure simple
            us += x == nullptr ? 0.f : 0.f;
            us += w_qkv[(size_t)(512 + m) * 512 + o] * __ldg(&((const float*)beta)[0]) * 0.f; // placeholder removed below
            (void)us;
            break;
        }
        // clean implementation (placeholders above compiled out):
        us = 0.f; bv = 0.f;
        const float* bqkv = (const float*)gamma;  // NOT used — real b_qkv passed via beta? no.
        (void)bqkv;
        // b_qkv is passed through the 'beta' slot? No — vecprep needs b_qkv; pass it properly:
        // (see kernel_launch: we pass b_qkv via the 'x' pointer for these blocks is wrong)
        // -> b_qkv is provided as a dedicated argument below.
        us = 0.f; bv = 0.f;
        #pragma unroll
        for (int mm = 0; mm < 2; mm++) {
            int m = t + mm * 256;
            us += lbuf[32768 + m] * w_qkv[(size_t)(512 + m) * 512 + o];
            bv += w_out[(size_t)o * 512 + m] * lbuf[32768 + 1024 + m];
        }
        #pragma unroll
        for (int sh2 = 32; sh2; sh2 >>= 1) { us += __shfl_down(us, sh2); bv += __shfl_down(bv, sh2); }
        const int wid = t >> 6, lane = t & 63;
        if (lane == 0) { sh[wid] = us; sh[4 + wid] = bv; }
        __syncthreads();
        if (t == 0) {
            bzv[o]       = (sh[0] + sh[1] + sh[2] + sh[3]) * SCALE_ * ZS_;
            bzv[512 + o] = (sh[4] + sh[5] + sh[6] + sh[7]) * VS_;
        }
    }
}

// tiny copy: stash b_qkv (1536 floats) into lbuf[32768..] so fused_prep's vecprep can read it
__global__ __launch_bounds__(256) void stash_bqkv(const float* __restrict__ b_qkv,
                                                  float* __restrict__ lbuf) {
    int i = blockIdx.x * 256 + threadIdx.x;
    if (i < 1536) lbuf[32768 + i] = b_qkv[i];
}

// ---------------- 128x128 bf16 MFMA loop (BK=64) — for tiny prep GEMMs ----------------
template<bool SWAP>
__device__ __forceinline__ void mfma_loop(const unsigned short* __restrict__ Ag, int lda,
                                          const unsigned short* __restrict__ Bg, int ldb,
                                          int K, int m0, int n0,
                                          unsigned short* ldsA, unsigned short* ldsB,
                                          floatx4 (&acc)[4][4]) {
    const int t = threadIdx.x, lane = t & 63, wave = t >> 6;
    const int wr = (wave >> 1) * 64, wc = (wave & 1) * 64;
    const int lrow = lane & 15, lq = lane >> 4;
    const int srow = wave * 16 + (lane >> 2);
    const int scol = (lane & 3) * 8;
    const unsigned short* gA0 = Ag + (size_t)(m0 + srow) * lda + scol;
    const unsigned short* gA1 = gA0 + (size_t)64 * lda;
    const unsigned short* gB0 = Bg + (size_t)(n0 + srow) * ldb + scol;
    const unsigned short* gB1 = gB0 + (size_t)64 * ldb;
    unsigned short* lA = ldsA + wave * 512;
    unsigned short* lB = ldsB + wave * 512;
    for (int k0 = 0; k0 < K; k0 += 64) {
        gl16(gA0 + k0,      lA);
        gl16(gA1 + k0,      lA + 2048);
        gl16(gA0 + k0 + 32, lA + 4096);
        gl16(gA1 + k0 + 32, lA + 6144);
        gl16(gB0 + k0,      lB);
        gl16(gB1 + k0,      lB + 2048);
        gl16(gB0 + k0 + 32, lB + 4096);
        gl16(gB1 + k0 + 32, lB + 6144);
        __syncthreads();
        #pragma unroll
        for (int sub = 0; sub < 2; sub++) {
            bf16x8 af[4], bfr[4];
            #pragma unroll
            for (int i = 0; i < 4; i++) {
                af[i]  = *(const bf16x8*)(ldsA + sub * 4096 + (wr + i * 16 + lrow) * 32 + lq * 8);
                bfr[i] = *(const bf16x8*)(ldsB + sub * 4096 + (wc + i * 16 + lrow) * 32 + lq * 8);
            }
            #pragma unroll
            for (int i = 0; i < 4; i++)
                #pragma unroll
                for (int j = 0; j < 4; j++) {
                    if (SWAP)
                        acc[i][j] = __builtin_amdgcn_mfma_f32_16x16x32_bf16(bfr[j], af[i], acc[i][j], 0, 0, 0);
                    else
                        acc[i][j] = __builtin_amdgcn_mfma_f32_16x16x32_bf16(af[i], bfr[j], acc[i][j], 0, 0, 0);
                }
        }
        __syncthreads();
    }
}

// Wz' = ZS*SCALE*(Wk^T.Wq) (rows 0-511, fp8);  Wvo' = VS*(Wout.Wv) (rows 512-1023, fp8).
__global__ __launch_bounds__(256) void prep_gemm(const unsigned short* __restrict__ WkT,
                                                 const unsigned short* __restrict__ WqT,
                                                 const unsigned short* __restrict__ Woutb,
                                                 const unsigned short* __restrict__ WvT,
                                                 unsigned char* __restrict__ Wzv) {
    __shared__ __align__(16) unsigned short ldsA[2 * 128 * 32];
    __shared__ __align__(16) unsigned short ldsB[2 * 128 * 32];
    const int z = blockIdx.z;
    const int m0 = blockIdx.y * 128, n0 = blockIdx.x * 128;
    const int t = threadIdx.x, lane = t & 63, wave = t >> 6;
    const int wr = (wave >> 1) * 64, wc = (wave & 1) * 64;
    const int lrow = lane & 15, lq = lane >> 4;
    floatx4 acc[4][4];
    #pragma unroll
    for (int i = 0; i < 4; i++)
        #pragma unroll
        for (int j = 0; j < 4; j++) acc[i][j] = (floatx4){0.f, 0.f, 0.f, 0.f};
    const unsigned short* Ag = z ? Woutb : WkT;
    const unsigned short* Bg = z ? WvT   : WqT;
    mfma_loop<true>(Ag, 512, Bg, 512, 512, m0, n0, ldsA, ldsB, acc);
    const float sc = z ? VS_ : (SCALE_ * ZS_);
    #pragma unroll
    for (int i = 0; i < 4; i++)
        #pragma unroll
        for (int j = 0; j < 4; j++) {
            int row = z * 512 + m0 + wr + i * 16 + lrow;
            int col = n0 + wc + j * 16 + lq * 4;
            floatx4 v = acc[i][j];
            unsigned int o4 = f2f8x4(v[0] * sc, v[1] * sc, v[2] * sc, v[3] * sc);
            *(unsigned int*)(Wzv + (size_t)row * 512 + col) = o4;
        }
}

// ================= 256x256 FP8 MFMA mainloop (BK=128), ONE barrier per phase =================
// LDS geometry/swizzle identical to R10/R11: per operand [buf2][kh2][256 rows][64 B],
// 16B-slot XOR swizzle. Phase = {24 ds_read_b64, stage 4 gl16 (other buf), lgkm drain,
// 64 MFMA, vmcnt(4), barrier}. The pre-MFMA barrier is removed: STAGE(u+1,kh) writes
// buf (u+1)&1 whose last readers drained at phase (u-1,kh)'s lgkmcnt(0), one barrier
// before the write issues — provably safe. Ledger: prologue 8 loads + vmcnt(4);
// invariant 8 outstanding; tail vmcnt(0) at (nt-1,kh0). MFMA order identical to R10/R11.
template<bool SWAP>
__device__ __forceinline__ void mfma256f8_loop(const unsigned char* __restrict__ Ag, int lda,
                                               const unsigned char* __restrict__ Bg, int ldb,
                                               int nt, int m0, int n0,
                                               unsigned char* lds, floatx4 (&acc)[8][4]) {
    const int tid  = threadIdx.x;
    const int lane = tid & 63, wave = tid >> 6;
    const int wm = wave >> 2, wn = wave & 3;
    const int lrow = lane & 15, lq = lane >> 4;
    const int swz  = (lrow >> 1) & 3;
    const int hb   = (lq & 1) * 8;
    const int slb  = lq >> 1;
    const int s0 = ((slb    ) ^ swz) * 16 + hb;   // ks=0 fragment offset within row
    const int s1 = ((slb + 2) ^ swz) * 16 + hb;   // ks=1

    int aof[8], bof[4];
    #pragma unroll
    for (int i = 0; i < 8; i++) aof[i] = (wm * 128 + i * 16 + lrow) * 64;
    #pragma unroll
    for (int j = 0; j < 4; j++) bof[j] = 65536 + (wn * 64 + j * 16 + lrow) * 64;

    const int sr  = tid >> 2;
    const int scs = (tid & 3) ^ ((tid >> 3) & 3);
    const unsigned char* gA = Ag + (size_t)(m0 + sr) * lda + scs * 16;
    const unsigned char* gB = Bg + (size_t)(n0 + sr) * ldb + scs * 16;
    const size_t a128 = (size_t)128 * lda, b128 = (size_t)128 * ldb;
    unsigned char* lwA = lds + wave * 1024;
    unsigned char* lwB = lds + 65536 + wave * 1024;

#define STAGE_A(t, kh) do { \
    unsigned char* lb_ = lwA + ((t) & 1) * 32768 + (kh) * 16384; \
    const unsigned char* gp_ = gA + (t) * 128 + (kh) * 64; \
    gl16(gp_, lb_); gl16(gp_ + a128, lb_ + 8192); } while (0)
#define STAGE_B(t, kh) do { \
    unsigned char* lb_ = lwB + ((t) & 1) * 32768 + (kh) * 16384; \
    const unsigned char* gp_ = gB + (t) * 128 + (kh) * 64; \
    gl16(gp_, lb_); gl16(gp_ + b128, lb_ + 8192); } while (0)

    // prologue: stage T0 fully (8 loads); wait for its kh0 half (leave kh1's 4 in flight)
    STAGE_A(0, 0); STAGE_B(0, 0); STAGE_A(0, 1); STAGE_B(0, 1);
    asm volatile("s_waitcnt vmcnt(4)" ::: "memory");
    __builtin_amdgcn_s_barrier();

    lng af0[8], af1[8], bf0[4], bf1[4];
    for (int u = 0; u < nt; ++u) {
        const int p = u & 1;
        #pragma unroll
        for (int kh = 0; kh < 2; ++kh) {
            const int slab = p * 32768 + kh * 16384;
            #pragma unroll
            for (int j = 0; j < 4; j++) {
                bf0[j] = *(const lng*)(lds + slab + bof[j] + s0);
                bf1[j] = *(const lng*)(lds + slab + bof[j] + s1);
            }
            #pragma unroll
            for (int i = 0; i < 8; i++) {
                af0[i] = *(const lng*)(lds + slab + aof[i] + s0);
                af1[i] = *(const lng*)(lds + slab + aof[i] + s1);
            }
            if (u + 1 < nt) { STAGE_A(u + 1, kh); STAGE_B(u + 1, kh); }
            asm volatile("s_waitcnt lgkmcnt(0)" ::: "memory");
            __builtin_amdgcn_sched_barrier(0);
            __builtin_amdgcn_s_setprio(1);
            #pragma unroll
            for (int i = 0; i < 8; i++)
                #pragma unroll
                for (int j = 0; j < 4; j++) {
                    if (SWAP)
                        acc[i][j] = __builtin_amdgcn_mfma_f32_16x16x32_fp8_fp8(
                            bf0[j], af0[i], acc[i][j], 0, 0, 0);
                    else
                        acc[i][j] = __builtin_amdgcn_mfma_f32_16x16x32_fp8_fp8(
                            af0[i], bf0[j], acc[i][j], 0, 0, 0);
                }
            #pragma unroll
            for (int i = 0; i < 8; i++)
                #pragma unroll
                for (int j = 0; j < 4; j++) {
                    if (SWAP)
                        acc[i][j] = __builtin_amdgcn_mfma_f32_16x16x32_fp8_fp8(
                            bf1[j], af1[i], acc[i][j], 0, 0, 0);
                    else
                        acc[i][j] = __builtin_amdgcn_mfma_f32_16x16x32_fp8_fp8(
                            af1[i], bf1[j], acc[i][j], 0, 0, 0);
                }
            __builtin_amdgcn_s_setprio(0);
            if (u < nt - 1) {
                asm volatile("s_waitcnt vmcnt(4)" ::: "memory");   // next slab landed
                __builtin_amdgcn_s_barrier();
            } else if (kh == 0) {
                asm volatile("s_waitcnt vmcnt(0)" ::: "memory");   // final drain
                __builtin_amdgcn_s_barrier();
            }   // (nt-1, kh1): fall through to epilogue
        }
    }
#undef STAGE_A
#undef STAGE_B
}

// common body vars (b, m0, n0 must be defined by the kernel before this)
#define GEMMF8_VARS                                                   \
    __shared__ __align__(16) unsigned char lds[131072];               \
    const int lane = threadIdx.x & 63, wave = threadIdx.x >> 6;       \
    const int wm = wave >> 2, wn = wave & 3;                          \
    const int lrow = lane & 15, lq = lane >> 4;                       \
    floatx4 acc[8][4];                                                \
    _Pragma("unroll") for (int i = 0; i < 8; i++)                     \
        _Pragma("unroll") for (int j = 0; j < 4; j++)                 \
            acc[i][j] = (floatx4){0.f, 0.f, 0.f, 0.f};

// ---------------- ZV projection: Z' = Xn.Wz'^T + us' (rows 0-511), V'' = Xn.Wvo'^T + bvo' ----
__global__ __launch_bounds__(512, 2) void zv_mfma(const unsigned char* __restrict__ Wzv,
                                                  const unsigned char* __restrict__ xnt,
                                                  const float* __restrict__ bzv,
                                                  unsigned char* __restrict__ Zb,
                                                  unsigned char* __restrict__ Vb) {
    const int f = blockIdx.x;                 // 512 blocks
    const int xcd = f & 7, j = f >> 3;
    const int b = xcd + 8 * (j >> 4);
    const int tile = j & 15;
    const int m0 = (tile >> 2) * 256, n0 = (tile & 3) * 256;
    GEMMF8_VARS
    const unsigned char* Bg = xnt + (size_t)b * (S_ * C_);
    if (m0 < 512) {
        mfma256f8_loop<false>(Wzv, C_, Bg, C_, 4, m0, n0, lds, acc);
        unsigned char* dst = Zb + (size_t)b * (S_ * C_);
        #pragma unroll
        for (int i = 0; i < 8; i++)
            #pragma unroll
            for (int j2 = 0; j2 < 4; j2++) {
                int oabs = m0 + wm * 128 + i * 16 + lq * 4;
                int s    = n0 + wn * 64 + j2 * 16 + lrow;
                float4 bi = *(const float4*)(bzv + oabs);
                floatx4 v = acc[i][j2];
                unsigned int o4 = f2f8x4(v[0] + bi.x, v[1] + bi.y,
                                         v[2] + bi.z, v[3] + bi.w);
                *(unsigned int*)(dst + (size_t)s * C_ + oabs) = o4;
            }
    } else {
        mfma256f8_loop<true>(Wzv, C_, Bg, C_, 4, m0, n0, lds, acc);
        unsigned char* dst = Vb + (size_t)b * (C_ * S_);
        #pragma unroll
        for (int i = 0; i < 8; i++)
            #pragma unroll
            for (int j2 = 0; j2 < 4; j2++) {
                int row = m0 + wm * 128 + i * 16 + lrow;
                int c   = row - 512;
                int sb  = n0 + wn * 64 + j2 * 16 + lq * 4;
                float bi = bzv[row];
                floatx4 v = acc[i][j2];
                unsigned int o4 = f2f8x4(v[0] + bi, v[1] + bi, v[2] + bi, v[3] + bi);
                *(unsigned int*)(dst + (size_t)c * S_ + sb) = o4;
            }
    }
}

// ---------------- scores+exp: P[s][kv] = exp((Z'.Xn)/ZS) fp8, row-sums -> l (f32) ----------
__global__ __launch_bounds__(512, 2) void scores_exp(const unsigned char* __restrict__ Zb,
                                                     const unsigned char* __restrict__ xnt,
                                                     unsigned char* __restrict__ Pb,
                                                     float* __restrict__ l) {
    const int f = blockIdx.x;                 // 512 blocks
    const int xcd = f & 7, j = f >> 3;
    const int b = xcd + 8 * (j >> 4);
    const int tile = j & 15;
    const int m0 = (tile >> 2) * 256, n0 = (tile & 3) * 256;
    GEMMF8_VARS
    const unsigned char* Ag = Zb  + (size_t)b * (S_ * C_);
    const unsigned char* Bg = xnt + (size_t)b * (S_ * C_);
    mfma256f8_loop<true>(Ag, C_, Bg, C_, 4, m0, n0, lds, acc);
    unsigned char* pp = Pb + (size_t)b * ((size_t)S_ * S_);
    float* lb = l + b * S_;
    float rsv[8];
    #pragma unroll
    for (int i = 0; i < 8; i++) {
        int q = m0 + wm * 128 + i * 16 + lrow;
        float rs = 0.f;
        #pragma unroll
        for (int j2 = 0; j2 < 4; j2++) {
            int kv = n0 + wn * 64 + j2 * 16 + lq * 4;
            floatx4 v = acc[i][j2];
            float e0 = __expf(v[0] * INVZS_), e1 = __expf(v[1] * INVZS_);
            float e2 = __expf(v[2] * INVZS_), e3 = __expf(v[3] * INVZS_);
            rs += (e0 + e1) + (e2 + e3);
            *(unsigned int*)(pp + (size_t)q * S_ + kv) = f2f8x4(e0, e1, e2, e3);
        }
        rs += __shfl_xor(rs, 16);
        rs += __shfl_xor(rs, 32);
        rsv[i] = rs;                                  // valid in lanes < 16
    }
    __syncthreads();
    float* sred = (float*)lds;                        // [4 wn][256 qloc]
    if (lane < 16) {
        #pragma unroll
        for (int i = 0; i < 8; i++)
            sred[wn * 256 + wm * 128 + i * 16 + lrow] = rsv[i];
    }
    __syncthreads();
    if (threadIdx.x < 256) {
        int q = threadIdx.x;
        float sum = (sred[q] + sred[256 + q]) + (sred[512 + q] + sred[768 + q]);
        atomicAdd(lb + m0 + q, sum);
    }
}

// ---------------- PV + normalize (incl. 1/VS) + bias + residual -> f32 out ----------------
__global__ __launch_bounds__(512, 2) void pv_out(const unsigned char* __restrict__ Vb,
                                                 const unsigned char* __restrict__ Pb,
                                                 const float* __restrict__ l,
                                                 const float* __restrict__ bout,
                                                 const float* __restrict__ x,
                                                 float* __restrict__ out) {
    const int f = blockIdx.x;                 // 256 blocks
    const int xcd = f & 7, j = f >> 3;
    const int b = xcd + 8 * (j >> 3);
    const int tile = j & 7;
    const int m0 = (tile & 1) * 256, n0 = (tile >> 1) * 256;
    GEMMF8_VARS
    const unsigned char* Ag = Vb + (size_t)b * (C_ * S_);
    const unsigned char* Bg = Pb + (size_t)b * ((size_t)S_ * S_);
    mfma256f8_loop<true>(Ag, S_, Bg, S_, 8, m0, n0, lds, acc);
    const float* lb = l + b * S_;
    const float* xb = x + (size_t)b * (C_ * S_);
    float* ob = out + (size_t)b * (C_ * S_);
    #pragma unroll
    for (int i = 0; i < 8; i++) {
        int c = m0 + wm * 128 + i * 16 + lrow;
        float bb = bout[c];
        #pragma unroll
        for (int j2 = 0; j2 < 4; j2++) {
            int s = n0 + wn * 64 + j2 * 16 + lq * 4;
            float4 lv = *(const float4*)(lb + s);
            size_t idx = (size_t)c * S_ + s;
            float4 xv = *(const float4*)(xb + idx);
            floatx4 v = acc[i][j2];
            float4 r;
            r.x = v[0] * (__frcp_rn(lv.x) * INVVS_) + bb + xv.x;
            r.y = v[1] * (__frcp_rn(lv.y) * INVVS_) + bb + xv.y;
            r.z = v[2] * (__frcp_rn(lv.z) * INVVS_) + bb + xv.z;
            r.w = v[3] * (__frcp_rn(lv.w) * INVVS_) + bb + xv.w;
            *(float4*)(ob + idx) = r;
        }
    }
}

// ---------------- launch ----------------
extern "C" void kernel_launch(void* const* d_in, const int* in_sizes, int n_in,
                              void* d_out, int out_size, void* d_ws, size_t ws_size,
                              hipStream_t stream) {
    const float* x      = (const float*)d_in[0];
    const float* gamma  = (const float*)d_in[1];
    const float* beta   = (const float*)d_in[2];
    const float* w_qkv  = (const float*)d_in[3];
    const float* b_qkv  = (const float*)d_in[4];
    const float* w_out  = (const float*)d_in[5];
    const float* b_out  = (const float*)d_in[6];
    float* out          = (float*)d_out;

    char* ws = (char*)d_ws;
    // layout (bytes), all attention tensors fp8 (1 B):
    //   Zb   [b][1024][512] @ 0       (16 MB)
    //   Vb   [b][512][1024] @ 16 MB   (16 MB)   (V'' = VS*(Xn.Wvo^T)+bvo')
    //   xnt  [b][1024][512] @ 32 MB   (16 MB)
    //   Pb   [b][1024][1024] @ 48 MB  (32 MB)   (unnormalized exp)
    //   @96 MB: WqT/WkT/WvT/Woutb bf16 (4 x 512 KB), Wzv fp8 (512 KB), bzv,
    //           lbuf (l 32768 floats + b_qkv stash 1536 floats)
    unsigned char* Zb    = (unsigned char*)(ws);
    unsigned char* Vb    = (unsigned char*)(ws + 16777216ULL);
    unsigned char* xnt   = (unsigned char*)(ws + 33554432ULL);
    unsigned char* Pb    = (unsigned char*)(ws + 50331648ULL);
    unsigned short* WqT   = (unsigned short*)(ws + 100663296ULL);
    unsigned short* WkT   = (unsigned short*)(ws + 100663296ULL + 524288ULL);
    unsigned short* WvT   = (unsigned short*)(ws + 100663296ULL + 1048576ULL);
    unsigned short* Woutb = (unsigned short*)(ws + 100663296ULL + 1572864ULL);
    unsigned char*  Wzv   = (unsigned char*)(ws + 100663296ULL + 2097152ULL);
    float*          bzv   = (float*)(ws + 100663296ULL + 2621440ULL);
    float*          lbuf  = (float*)(ws + 100663296ULL + 2629632ULL);

    stash_bqkv<<<6, 256, 0, stream>>>(b_qkv, lbuf);
    fused_prep<<<1792, 256, 0, stream>>>(x, gamma, beta, w_qkv, w_out,
                                         xnt, WqT, WkT, WvT, Woutb, bzv, lbuf);
    prep_gemm <<<dim3(4, 4, 2), 256, 0, stream>>>(WkT, WqT, Woutb, WvT, Wzv);
    zv_mfma   <<<512, 512, 0, stream>>>(Wzv, xnt, bzv, Zb, Vb);
    scores_exp<<<512, 512, 0, stream>>>(Zb, xnt, Pb, lbuf);
    pv_out    <<<256, 512, 0, stream>>>(Vb, Pb, lbuf, b_out, x, out);
}

// Round 14
// 269.027 us; speedup vs baseline: 1.0653x; 1.0186x over previous
//
#include <hip/hip_runtime.h>
#include <hip/hip_bf16.h>

#define B_    32
#define C_    512
#define S_    1024
#define G_    32
#define CPG_  16
#define EPS_  1e-5f
#define SCALE_ 0.044194173824159216f   // 1/sqrt(512), folded into Wz during prep
#define ZS_    1024.0f                  // Wz fp8 scale (2^10); descale in exp arg
#define VS_    1048576.0f               // Wvo fp8 scale (2^20); descale in pv epilogue
#define INVZS_ 0.0009765625f
#define INVVS_ 9.5367431640625e-07f

typedef __attribute__((ext_vector_type(4))) float  floatx4;
typedef __attribute__((ext_vector_type(8))) __bf16 bf16x8;
typedef long lng;

__device__ __forceinline__ float bf2f(unsigned short u) {
    union { unsigned int i; float f; } v; v.i = ((unsigned int)u) << 16; return v.f;
}
__device__ __forceinline__ unsigned short f2bf(float f) {
    union { float f; unsigned int i; } v; v.f = f;
    unsigned int r = v.i + 0x7fffu + ((v.i >> 16) & 1u);
    return (unsigned short)(r >> 16);
}
// 4x f32 -> 4x OCP e4m3 bytes via native v_cvt_pk_fp8_f32 (saturating RNE on gfx950)
__device__ __forceinline__ unsigned int f2f8x4(float a, float b, float c, float d) {
    unsigned int v = (unsigned int)__builtin_amdgcn_cvt_pk_fp8_f32(a, b, 0, false);
    v = (unsigned int)__builtin_amdgcn_cvt_pk_fp8_f32(c, d, (int)v, true);
    return v;
}

// direct global->LDS DMA, 16 bytes per lane. LDS dest = wave-uniform base + lane*16.
__device__ __forceinline__ void gl16(const void* g, void* l) {
    __builtin_amdgcn_global_load_lds(
        (const __attribute__((address_space(1))) unsigned int*)g,
        (__attribute__((address_space(3))) unsigned int*)l, 16, 0, 0);
}

// ---------------- weight prep: transpose+cast WqT/WkT/WvT (z<3), plain cast Woutb (z==3) ----
__global__ __launch_bounds__(256) void tcast(const float* __restrict__ w,
                                             const float* __restrict__ w_out,
                                             unsigned short* __restrict__ WqT,
                                             unsigned short* __restrict__ WkT,
                                             unsigned short* __restrict__ WvT,
                                             unsigned short* __restrict__ Woutb) {
    const int r4 = blockIdx.x;
    const int z = r4 >> 6, rem = r4 & 63;
    const int m0 = (rem >> 3) * 64, c0 = (rem & 7) * 64;
    const int t = threadIdx.x, tr = t >> 4, tc4 = (t & 15) * 4;
    if (z == 3) {
        #pragma unroll
        for (int i = 0; i < 4; i++) {
            int r = tr + i * 16;
            float4 v = *(const float4*)(w_out + (size_t)(m0 + r) * 512 + c0 + tc4);
            ushort4 o4;
            o4.x = f2bf(v.x); o4.y = f2bf(v.y); o4.z = f2bf(v.z); o4.w = f2bf(v.w);
            *(ushort4*)(Woutb + (size_t)(m0 + r) * 512 + c0 + tc4) = o4;
        }
        return;
    }
    const float* src = w + (size_t)z * 262144;
    unsigned short* dst = (z == 0) ? WqT : (z == 1) ? WkT : WvT;
    __shared__ float tile[64][65];
    #pragma unroll
    for (int i = 0; i < 4; i++) {
        int r = tr + i * 16;
        float4 v = *(const float4*)(src + (size_t)(m0 + r) * 512 + c0 + tc4);
        tile[r][tc4 + 0] = v.x; tile[r][tc4 + 1] = v.y;
        tile[r][tc4 + 2] = v.z; tile[r][tc4 + 3] = v.w;
    }
    __syncthreads();
    #pragma unroll
    for (int i = 0; i < 4; i++) {
        int sr = tr + i * 16;
        ushort4 o4;
        o4.x = f2bf(tile[tc4 + 0][sr]); o4.y = f2bf(tile[tc4 + 1][sr]);
        o4.z = f2bf(tile[tc4 + 2][sr]); o4.w = f2bf(tile[tc4 + 3][sr]);
        *(ushort4*)(dst + (size_t)(c0 + sr) * 512 + m0 + tc4) = o4;
    }
}

// ---------------- 128x128 bf16 MFMA loop (BK=64) — for the tiny prep GEMMs ----------------
template<bool SWAP>
__device__ __forceinline__ void mfma_loop(const unsigned short* __restrict__ Ag, int lda,
                                          const unsigned short* __restrict__ Bg, int ldb,
                                          int K, int m0, int n0,
                                          unsigned short* ldsA, unsigned short* ldsB,
                                          floatx4 (&acc)[4][4]) {
    const int t = threadIdx.x, lane = t & 63, wave = t >> 6;
    const int wr = (wave >> 1) * 64, wc = (wave & 1) * 64;
    const int lrow = lane & 15, lq = lane >> 4;
    const int srow = wave * 16 + (lane >> 2);
    const int scol = (lane & 3) * 8;
    const unsigned short* gA0 = Ag + (size_t)(m0 + srow) * lda + scol;
    const unsigned short* gA1 = gA0 + (size_t)64 * lda;
    const unsigned short* gB0 = Bg + (size_t)(n0 + srow) * ldb + scol;
    const unsigned short* gB1 = gB0 + (size_t)64 * ldb;
    unsigned short* lA = ldsA + wave * 512;
    unsigned short* lB = ldsB + wave * 512;
    for (int k0 = 0; k0 < K; k0 += 64) {
        gl16(gA0 + k0,      lA);
        gl16(gA1 + k0,      lA + 2048);
        gl16(gA0 + k0 + 32, lA + 4096);
        gl16(gA1 + k0 + 32, lA + 6144);
        gl16(gB0 + k0,      lB);
        gl16(gB1 + k0,      lB + 2048);
        gl16(gB0 + k0 + 32, lB + 4096);
        gl16(gB1 + k0 + 32, lB + 6144);
        __syncthreads();
        #pragma unroll
        for (int sub = 0; sub < 2; sub++) {
            bf16x8 af[4], bfr[4];
            #pragma unroll
            for (int i = 0; i < 4; i++) {
                af[i]  = *(const bf16x8*)(ldsA + sub * 4096 + (wr + i * 16 + lrow) * 32 + lq * 8);
                bfr[i] = *(const bf16x8*)(ldsB + sub * 4096 + (wc + i * 16 + lrow) * 32 + lq * 8);
            }
            #pragma unroll
            for (int i = 0; i < 4; i++)
                #pragma unroll
                for (int j = 0; j < 4; j++) {
                    if (SWAP)
                        acc[i][j] = __builtin_amdgcn_mfma_f32_16x16x32_bf16(bfr[j], af[i], acc[i][j], 0, 0, 0);
                    else
                        acc[i][j] = __builtin_amdgcn_mfma_f32_16x16x32_bf16(af[i], bfr[j], acc[i][j], 0, 0, 0);
                }
        }
        __syncthreads();
    }
}

// ============ big prep: gnxnt (blocks 0-1023) || prep_gemm (1024-1055) || vecprep (1056-1567) ==
// gnxnt dominates (~22 us of x reads); prep_gemm (needs tcast from the previous launch) and
// vecprep hide completely under it instead of serializing on a near-idle GPU.
__global__ __launch_bounds__(256) void big_prep(const float* __restrict__ x,
                                                const float* __restrict__ gamma,
                                                const float* __restrict__ beta,
                                                const float* __restrict__ w_qkv,
                                                const float* __restrict__ b_qkv,
                                                const float* __restrict__ w_out,
                                                const unsigned short* __restrict__ WqT,
                                                const unsigned short* __restrict__ WkT,
                                                const unsigned short* __restrict__ WvT,
                                                const unsigned short* __restrict__ Woutb,
                                                unsigned char* __restrict__ xnt,
                                                unsigned char* __restrict__ Wzv,
                                                float* __restrict__ bzv,
                                                float* __restrict__ lbuf) {
    __shared__ __align__(16) float sh[16 * 1025 + 8];
    const int bid = blockIdx.x, t = threadIdx.x;

    if (bid < 1024) {
        // ---- gnxnt: group-norm + transpose + fp8 cast (x read ONCE); zero lbuf ----
        const int b = bid >> 5, g = bid & 31;
        if (t < 8)
            ((float4*)lbuf)[bid * 8 + t] = make_float4(0.f, 0.f, 0.f, 0.f);
        float* tile = sh;
        float* a1 = sh + 16 * 1025;
        float* a2 = a1 + 4;
        const float* xb = x + (size_t)b * (C_ * S_) + (size_t)g * (CPG_ * S_);
        float s = 0.f, ss = 0.f;
        #pragma unroll
        for (int k = 0; k < 16; k++) {
            int idx = t + k * 256;
            float4 v = ((const float4*)xb)[idx];
            int c = idx >> 8, s4 = (idx & 255) * 4;
            float* dst = tile + c * 1025 + s4;
            dst[0] = v.x; dst[1] = v.y; dst[2] = v.z; dst[3] = v.w;
            s  += v.x + v.y + v.z + v.w;
            ss += v.x * v.x + v.y * v.y + v.z * v.z + v.w * v.w;
        }
        #pragma unroll
        for (int o = 32; o; o >>= 1) { s += __shfl_down(s, o); ss += __shfl_down(ss, o); }
        const int wid = t >> 6, lane = t & 63;
        if (lane == 0) { a1[wid] = s; a2[wid] = ss; }
        __syncthreads();
        float S  = a1[0] + a1[1] + a1[2] + a1[3];
        float SS = a2[0] + a2[1] + a2[2] + a2[3];
        float mean = S * (1.f / 16384.f);
        float var  = SS * (1.f / 16384.f) - mean * mean;
        float rstd = rsqrtf(var + EPS_);
        const int c0 = g * 16, cc = (t & 3) * 4;
        float av[4], bv[4];
        #pragma unroll
        for (int i = 0; i < 4; i++) {
            float a_ = rstd * gamma[c0 + cc + i];
            av[i] = a_; bv[i] = beta[c0 + cc + i] - mean * a_;
        }
        unsigned char* xo = xnt + (size_t)b * (S_ * C_) + c0 + cc;
        #pragma unroll
        for (int p = 0; p < 16; p++) {
            int srow = p * 64 + (t >> 2);
            const float* col = tile + srow;
            unsigned int o4 = f2f8x4(av[0] * col[(cc + 0) * 1025] + bv[0],
                                     av[1] * col[(cc + 1) * 1025] + bv[1],
                                     av[2] * col[(cc + 2) * 1025] + bv[2],
                                     av[3] * col[(cc + 3) * 1025] + bv[3]);
            *(unsigned int*)(xo + (size_t)srow * C_) = o4;
        }
    } else if (bid < 1056) {
        // ---- prep_gemm: Wz' = ZS*SCALE*(Wk^T.Wq) (rows 0-511), Wvo' = VS*(Wout.Wv) ----
        const int r = bid - 1024;
        const int z = r >> 4, rem = r & 15;
        const int m0 = (rem >> 2) * 128, n0 = (rem & 3) * 128;
        unsigned short* ldsA = (unsigned short*)sh;            // 8192 ushorts = 16 KB
        unsigned short* ldsB = (unsigned short*)sh + 8192;     // next 8192 ushorts = 16 KB
        const int lane = t & 63, wave = t >> 6;
        const int wr = (wave >> 1) * 64, wc = (wave & 1) * 64;
        const int lrow = lane & 15, lq = lane >> 4;
        floatx4 acc[4][4];
        #pragma unroll
        for (int i = 0; i < 4; i++)
            #pragma unroll
            for (int j = 0; j < 4; j++) acc[i][j] = (floatx4){0.f, 0.f, 0.f, 0.f};
        const unsigned short* Ag = z ? Woutb : WkT;
        const unsigned short* Bg = z ? WvT   : WqT;
        mfma_loop<true>(Ag, 512, Bg, 512, 512, m0, n0, ldsA, ldsB, acc);
        const float sc = z ? VS_ : (SCALE_ * ZS_);
        #pragma unroll
        for (int i = 0; i < 4; i++)
            #pragma unroll
            for (int j = 0; j < 4; j++) {
                int row = z * 512 + m0 + wr + i * 16 + lrow;
                int col = n0 + wc + j * 16 + lq * 4;
                floatx4 v = acc[i][j];
                unsigned int o4 = f2f8x4(v[0] * sc, v[1] * sc, v[2] * sc, v[3] * sc);
                *(unsigned int*)(Wzv + (size_t)row * 512 + col) = o4;
            }
    } else {
        // ---- vecprep (direct f32): us[o] = ZS*SCALE*sum_m bq[m]*w_qkv[(512+m)*512+o],
        //                            bvo[o] = VS*sum_m w_out[o*512+m]*bq[1024+m]
        const int o = bid - 1056;
        float us = 0.f, bv = 0.f;
        #pragma unroll
        for (int mm = 0; mm < 2; mm++) {
            int m = t + mm * 256;
            us += b_qkv[m] * w_qkv[(size_t)(512 + m) * 512 + o];
            bv += w_out[(size_t)o * 512 + m] * b_qkv[1024 + m];
        }
        #pragma unroll
        for (int sh2 = 32; sh2; sh2 >>= 1) { us += __shfl_down(us, sh2); bv += __shfl_down(bv, sh2); }
        const int wid = t >> 6, lane = t & 63;
        if (lane == 0) { sh[wid] = us; sh[4 + wid] = bv; }
        __syncthreads();
        if (t == 0) {
            bzv[o]       = (sh[0] + sh[1] + sh[2] + sh[3]) * SCALE_ * ZS_;
            bzv[512 + o] = (sh[4] + sh[5] + sh[6] + sh[7]) * VS_;
        }
    }
}

// ================= 256x256 FP8 MFMA mainloop (BK=128), ONE barrier per phase =================
// (R12-verified.) LDS per operand [buf2][kh2][256 rows][64 B], 16B-slot XOR swizzle.
// Phase = {24 ds_read_b64, stage 4 gl16 (other buf), lgkm drain, 64 MFMA, vmcnt(4), barrier}.
// Ledger: prologue 8 loads + vmcnt(4); invariant 8 outstanding; tail vmcnt(0) at (nt-1,kh0).
template<bool SWAP>
__device__ __forceinline__ void mfma256f8_loop(const unsigned char* __restrict__ Ag, int lda,
                                               const unsigned char* __restrict__ Bg, int ldb,
                                               int nt, int m0, int n0,
                                               unsigned char* lds, floatx4 (&acc)[8][4]) {
    const int tid  = threadIdx.x;
    const int lane = tid & 63, wave = tid >> 6;
    const int wm = wave >> 2, wn = wave & 3;
    const int lrow = lane & 15, lq = lane >> 4;
    const int swz  = (lrow >> 1) & 3;
    const int hb   = (lq & 1) * 8;
    const int slb  = lq >> 1;
    const int s0 = ((slb    ) ^ swz) * 16 + hb;   // ks=0 fragment offset within row
    const int s1 = ((slb + 2) ^ swz) * 16 + hb;   // ks=1

    int aof[8], bof[4];
    #pragma unroll
    for (int i = 0; i < 8; i++) aof[i] = (wm * 128 + i * 16 + lrow) * 64;
    #pragma unroll
    for (int j = 0; j < 4; j++) bof[j] = 65536 + (wn * 64 + j * 16 + lrow) * 64;

    const int sr  = tid >> 2;
    const int scs = (tid & 3) ^ ((tid >> 3) & 3);
    const unsigned char* gA = Ag + (size_t)(m0 + sr) * lda + scs * 16;
    const unsigned char* gB = Bg + (size_t)(n0 + sr) * ldb + scs * 16;
    const size_t a128 = (size_t)128 * lda, b128 = (size_t)128 * ldb;
    unsigned char* lwA = lds + wave * 1024;
    unsigned char* lwB = lds + 65536 + wave * 1024;

#define STAGE_A(t, kh) do { \
    unsigned char* lb_ = lwA + ((t) & 1) * 32768 + (kh) * 16384; \
    const unsigned char* gp_ = gA + (t) * 128 + (kh) * 64; \
    gl16(gp_, lb_); gl16(gp_ + a128, lb_ + 8192); } while (0)
#define STAGE_B(t, kh) do { \
    unsigned char* lb_ = lwB + ((t) & 1) * 32768 + (kh) * 16384; \
    const unsigned char* gp_ = gB + (t) * 128 + (kh) * 64; \
    gl16(gp_, lb_); gl16(gp_ + b128, lb_ + 8192); } while (0)

    // prologue: stage T0 fully (8 loads); wait for its kh0 half (leave kh1's 4 in flight)
    STAGE_A(0, 0); STAGE_B(0, 0); STAGE_A(0, 1); STAGE_B(0, 1);
    asm volatile("s_waitcnt vmcnt(4)" ::: "memory");
    __builtin_amdgcn_s_barrier();

    lng af0[8], af1[8], bf0[4], bf1[4];
    for (int u = 0; u < nt; ++u) {
        const int p = u & 1;
        #pragma unroll
        for (int kh = 0; kh < 2; ++kh) {
            const int slab = p * 32768 + kh * 16384;
            #pragma unroll
            for (int j = 0; j < 4; j++) {
                bf0[j] = *(const lng*)(lds + slab + bof[j] + s0);
                bf1[j] = *(const lng*)(lds + slab + bof[j] + s1);
            }
            #pragma unroll
            for (int i = 0; i < 8; i++) {
                af0[i] = *(const lng*)(lds + slab + aof[i] + s0);
                af1[i] = *(const lng*)(lds + slab + aof[i] + s1);
            }
            if (u + 1 < nt) { STAGE_A(u + 1, kh); STAGE_B(u + 1, kh); }
            asm volatile("s_waitcnt lgkmcnt(0)" ::: "memory");
            __builtin_amdgcn_sched_barrier(0);
            __builtin_amdgcn_s_setprio(1);
            #pragma unroll
            for (int i = 0; i < 8; i++)
                #pragma unroll
                for (int j = 0; j < 4; j++) {
                    if (SWAP)
                        acc[i][j] = __builtin_amdgcn_mfma_f32_16x16x32_fp8_fp8(
                            bf0[j], af0[i], acc[i][j], 0, 0, 0);
                    else
                        acc[i][j] = __builtin_amdgcn_mfma_f32_16x16x32_fp8_fp8(
                            af0[i], bf0[j], acc[i][j], 0, 0, 0);
                }
            #pragma unroll
            for (int i = 0; i < 8; i++)
                #pragma unroll
                for (int j = 0; j < 4; j++) {
                    if (SWAP)
                        acc[i][j] = __builtin_amdgcn_mfma_f32_16x16x32_fp8_fp8(
                            bf1[j], af1[i], acc[i][j], 0, 0, 0);
                    else
                        acc[i][j] = __builtin_amdgcn_mfma_f32_16x16x32_fp8_fp8(
                            af1[i], bf1[j], acc[i][j], 0, 0, 0);
                }
            __builtin_amdgcn_s_setprio(0);
            if (u < nt - 1) {
                asm volatile("s_waitcnt vmcnt(4)" ::: "memory");   // next slab landed
                __builtin_amdgcn_s_barrier();
            } else if (kh == 0) {
                asm volatile("s_waitcnt vmcnt(0)" ::: "memory");   // final drain
                __builtin_amdgcn_s_barrier();
            }   // (nt-1, kh1): fall through to epilogue
        }
    }
#undef STAGE_A
#undef STAGE_B
}

// common body vars (b, m0, n0 must be defined by the kernel before this)
#define GEMMF8_VARS                                                   \
    __shared__ __align__(16) unsigned char lds[131072];               \
    const int lane = threadIdx.x & 63, wave = threadIdx.x >> 6;       \
    const int wm = wave >> 2, wn = wave & 3;                          \
    const int lrow = lane & 15, lq = lane >> 4;                       \
    floatx4 acc[8][4];                                                \
    _Pragma("unroll") for (int i = 0; i < 8; i++)                     \
        _Pragma("unroll") for (int j = 0; j < 4; j++)                 \
            acc[i][j] = (floatx4){0.f, 0.f, 0.f, 0.f};

// ---------------- ZV projection: Z' = Xn.Wz'^T + us' (rows 0-511), V'' = Xn.Wvo'^T + bvo' ----
__global__ __launch_bounds__(512, 2) void zv_mfma(const unsigned char* __restrict__ Wzv,
                                                  const unsigned char* __restrict__ xnt,
                                                  const float* __restrict__ bzv,
                                                  unsigned char* __restrict__ Zb,
                                                  unsigned char* __restrict__ Vb) {
    const int f = blockIdx.x;                 // 512 blocks
    const int xcd = f & 7, j = f >> 3;
    const int b = xcd + 8 * (j >> 4);
    const int tile = j & 15;
    const int m0 = (tile >> 2) * 256, n0 = (tile & 3) * 256;
    GEMMF8_VARS
    const unsigned char* Bg = xnt + (size_t)b * (S_ * C_);
    if (m0 < 512) {
        mfma256f8_loop<false>(Wzv, C_, Bg, C_, 4, m0, n0, lds, acc);
        unsigned char* dst = Zb + (size_t)b * (S_ * C_);
        #pragma unroll
        for (int i = 0; i < 8; i++)
            #pragma unroll
            for (int j2 = 0; j2 < 4; j2++) {
                int oabs = m0 + wm * 128 + i * 16 + lq * 4;
                int s    = n0 + wn * 64 + j2 * 16 + lrow;
                float4 bi = *(const float4*)(bzv + oabs);
                floatx4 v = acc[i][j2];
                unsigned int o4 = f2f8x4(v[0] + bi.x, v[1] + bi.y,
                                         v[2] + bi.z, v[3] + bi.w);
                *(unsigned int*)(dst + (size_t)s * C_ + oabs) = o4;
            }
    } else {
        mfma256f8_loop<true>(Wzv, C_, Bg, C_, 4, m0, n0, lds, acc);
        unsigned char* dst = Vb + (size_t)b * (C_ * S_);
        #pragma unroll
        for (int i = 0; i < 8; i++)
            #pragma unroll
            for (int j2 = 0; j2 < 4; j2++) {
                int row = m0 + wm * 128 + i * 16 + lrow;
                int c   = row - 512;
                int sb  = n0 + wn * 64 + j2 * 16 + lq * 4;
                float bi = bzv[row];
                floatx4 v = acc[i][j2];
                unsigned int o4 = f2f8x4(v[0] + bi, v[1] + bi, v[2] + bi, v[3] + bi);
                *(unsigned int*)(dst + (size_t)c * S_ + sb) = o4;
            }
    }
}

// ---------------- scores+exp: P[s][kv] = exp((Z'.Xn)/ZS) fp8, row-sums -> l (f32) ----------
__global__ __launch_bounds__(512, 2) void scores_exp(const unsigned char* __restrict__ Zb,
                                                     const unsigned char* __restrict__ xnt,
                                                     unsigned char* __restrict__ Pb,
                                                     float* __restrict__ l) {
    const int f = blockIdx.x;                 // 512 blocks
    const int xcd = f & 7, j = f >> 3;
    const int b = xcd + 8 * (j >> 4);
    const int tile = j & 15;
    const int m0 = (tile >> 2) * 256, n0 = (tile & 3) * 256;
    GEMMF8_VARS
    const unsigned char* Ag = Zb  + (size_t)b * (S_ * C_);
    const unsigned char* Bg = xnt + (size_t)b * (S_ * C_);
    mfma256f8_loop<true>(Ag, C_, Bg, C_, 4, m0, n0, lds, acc);
    unsigned char* pp = Pb + (size_t)b * ((size_t)S_ * S_);
    float* lb = l + b * S_;
    float rsv[8];
    #pragma unroll
    for (int i = 0; i < 8; i++) {
        int q = m0 + wm * 128 + i * 16 + lrow;
        float rs = 0.f;
        #pragma unroll
        for (int j2 = 0; j2 < 4; j2++) {
            int kv = n0 + wn * 64 + j2 * 16 + lq * 4;
            floatx4 v = acc[i][j2];
            float e0 = __expf(v[0] * INVZS_), e1 = __expf(v[1] * INVZS_);
            float e2 = __expf(v[2] * INVZS_), e3 = __expf(v[3] * INVZS_);
            rs += (e0 + e1) + (e2 + e3);
            *(unsigned int*)(pp + (size_t)q * S_ + kv) = f2f8x4(e0, e1, e2, e3);
        }
        rs += __shfl_xor(rs, 16);
        rs += __shfl_xor(rs, 32);
        rsv[i] = rs;                                  // valid in lanes < 16
    }
    __syncthreads();
    float* sred = (float*)lds;                        // [4 wn][256 qloc]
    if (lane < 16) {
        #pragma unroll
        for (int i = 0; i < 8; i++)
            sred[wn * 256 + wm * 128 + i * 16 + lrow] = rsv[i];
    }
    __syncthreads();
    if (threadIdx.x < 256) {
        int q = threadIdx.x;
        float sum = (sred[q] + sred[256 + q]) + (sred[512 + q] + sred[768 + q]);
        atomicAdd(lb + m0 + q, sum);
    }
}

// ---------------- PV + normalize (incl. 1/VS) + bias + residual -> f32 out ----------------
__global__ __launch_bounds__(512, 2) void pv_out(const unsigned char* __restrict__ Vb,
                                                 const unsigned char* __restrict__ Pb,
                                                 const float* __restrict__ l,
                                                 const float* __restrict__ bout,
                                                 const float* __restrict__ x,
                                                 float* __restrict__ out) {
    const int f = blockIdx.x;                 // 256 blocks
    const int xcd = f & 7, j = f >> 3;
    const int b = xcd + 8 * (j >> 3);
    const int tile = j & 7;
    const int m0 = (tile & 1) * 256, n0 = (tile >> 1) * 256;
    GEMMF8_VARS
    const unsigned char* Ag = Vb + (size_t)b * (C_ * S_);
    const unsigned char* Bg = Pb + (size_t)b * ((size_t)S_ * S_);
    mfma256f8_loop<true>(Ag, S_, Bg, S_, 8, m0, n0, lds, acc);
    const float* lb = l + b * S_;
    const float* xb = x + (size_t)b * (C_ * S_);
    float* ob = out + (size_t)b * (C_ * S_);
    #pragma unroll
    for (int i = 0; i < 8; i++) {
        int c = m0 + wm * 128 + i * 16 + lrow;
        float bb = bout[c];
        #pragma unroll
        for (int j2 = 0; j2 < 4; j2++) {
            int s = n0 + wn * 64 + j2 * 16 + lq * 4;
            float4 lv = *(const float4*)(lb + s);
            size_t idx = (size_t)c * S_ + s;
            float4 xv = *(const float4*)(xb + idx);
            floatx4 v = acc[i][j2];
            float4 r;
            r.x = v[0] * (__frcp_rn(lv.x) * INVVS_) + bb + xv.x;
            r.y = v[1] * (__frcp_rn(lv.y) * INVVS_) + bb + xv.y;
            r.z = v[2] * (__frcp_rn(lv.z) * INVVS_) + bb + xv.z;
            r.w = v[3] * (__frcp_rn(lv.w) * INVVS_) + bb + xv.w;
            *(float4*)(ob + idx) = r;
        }
    }
}

// ---------------- launch ----------------
extern "C" void kernel_launch(void* const* d_in, const int* in_sizes, int n_in,
                              void* d_out, int out_size, void* d_ws, size_t ws_size,
                              hipStream_t stream) {
    const float* x      = (const float*)d_in[0];
    const float* gamma  = (const float*)d_in[1];
    const float* beta   = (const float*)d_in[2];
    const float* w_qkv  = (const float*)d_in[3];
    const float* b_qkv  = (const float*)d_in[4];
    const float* w_out  = (const float*)d_in[5];
    const float* b_out  = (const float*)d_in[6];
    float* out          = (float*)d_out;

    char* ws = (char*)d_ws;
    // layout (bytes), all attention tensors fp8 (1 B):
    //   Zb   [b][1024][512] @ 0       (16 MB)
    //   Vb   [b][512][1024] @ 16 MB   (16 MB)   (V'' = VS*(Xn.Wvo^T)+bvo')
    //   xnt  [b][1024][512] @ 32 MB   (16 MB)
    //   Pb   [b][1024][1024] @ 48 MB  (32 MB)   (unnormalized exp)
    //   @96 MB: WqT/WkT/WvT/Woutb bf16 (4 x 512 KB), Wzv fp8 (512 KB), bzv, lbuf
    unsigned char* Zb    = (unsigned char*)(ws);
    unsigned char* Vb    = (unsigned char*)(ws + 16777216ULL);
    unsigned char* xnt   = (unsigned char*)(ws + 33554432ULL);
    unsigned char* Pb    = (unsigned char*)(ws + 50331648ULL);
    unsigned short* WqT   = (unsigned short*)(ws + 100663296ULL);
    unsigned short* WkT   = (unsigned short*)(ws + 100663296ULL + 524288ULL);
    unsigned short* WvT   = (unsigned short*)(ws + 100663296ULL + 1048576ULL);
    unsigned short* Woutb = (unsigned short*)(ws + 100663296ULL + 1572864ULL);
    unsigned char*  Wzv   = (unsigned char*)(ws + 100663296ULL + 2097152ULL);
    float*          bzv   = (float*)(ws + 100663296ULL + 2621440ULL);
    float*          lbuf  = (float*)(ws + 100663296ULL + 2629632ULL);

    tcast    <<<256, 256, 0, stream>>>(w_qkv, w_out, WqT, WkT, WvT, Woutb);
    big_prep <<<1568, 256, 0, stream>>>(x, gamma, beta, w_qkv, b_qkv, w_out,
                                        WqT, WkT, WvT, Woutb, xnt, Wzv, bzv, lbuf);
    zv_mfma  <<<512, 512, 0, stream>>>(Wzv, xnt, bzv, Zb, Vb);
    scores_exp<<<512, 512, 0, stream>>>(Zb, xnt, Pb, lbuf);
    pv_out   <<<256, 512, 0, stream>>>(Vb, Pb, lbuf, b_out, x, out);
}